// Round 7
// baseline (297.598 us; speedup 1.0000x reference)
//
#include <hip/hip_runtime.h>
#include <hip/hip_fp16.h>
#include <stdint.h>

// AQT int8 MLP: M=8192, C=1024, H=4096. All I/O float32.
// Exact path: fake_quant values are q/s (integer q), so xq@wq is exact in int32 MFMA.
// 5 dispatches: stats -> quant(x,W1t,W2t) -> GEMM1(h fp16 + block hmax) -> quant_h -> GEMM2.
// GEMM: 128x128 block, 2x2 waves, wave-tile 64x64 = 2x2 of mfma_i32_32x32x32_i8,
// BK=64, LDS double-buffer (1 barrier/step), tiles stored in MFMA-FRAGMENT ORDER:
// one 32x32x32 fragment = 64 lanes x 16B = one wave global_load_lds; compute reads
// base+lane*16 (lane-contiguous -> conflict-free by construction).
// Grid is (x=m-tiles, y=n-tiles) so XCD j owns m=j mod 8 stripes (L2 locality).

#define EPSQ 1e-6f
typedef int v4i __attribute__((ext_vector_type(4)));
typedef int v16i __attribute__((ext_vector_type(16)));

__device__ __forceinline__ int8_t quant1(float x, float s) {
  return (int8_t)(int)fminf(fmaxf(rintf(x * s), -127.f), 127.f);
}
__device__ __forceinline__ void async16(const int8_t* g, int8_t* l) {
  __builtin_amdgcn_global_load_lds(
      (const __attribute__((address_space(1))) void*)g,
      (__attribute__((address_space(3))) void*)l, 16, 0, 0);
}
__device__ __forceinline__ unsigned short f2h(float f) {
  __half h = __float2half(f);
  return *(unsigned short*)&h;
}
__device__ __forceinline__ float h2f(unsigned short u) {
  __half h = *(__half*)&u;
  return __half2float(h);
}
__device__ __forceinline__ float4 max4(float4 m, float4 v) {
  m.x = fmaxf(m.x, fabsf(v.x)); m.y = fmaxf(m.y, fabsf(v.y));
  m.z = fmaxf(m.z, fabsf(v.z)); m.w = fmaxf(m.w, fabsf(v.w));
  return m;
}

// ===== dispatch 1: stats. W1: 16 rowsplits x 4 colgroups; W2: 64 rowsplits;
// x masked absmax: 1024 blk. =====
__global__ __launch_bounds__(256) void k_stats(
    const float* __restrict__ x, const float* __restrict__ mask,
    const float* __restrict__ W1, const float* __restrict__ W2,
    float* __restrict__ pmaxX, float* __restrict__ pcm1, float* __restrict__ pcm2) {
  const int bx = blockIdx.x, tid = threadIdx.x;
  if (bx < 64) {                       // W1 [1024,4096]
    const int sp = bx & 15, cg = bx >> 4;
    const int col = cg * 1024 + tid * 4;
    float4 m = {0.f, 0.f, 0.f, 0.f};
#pragma unroll 8
    for (int r = 0; r < 64; ++r)
      m = max4(m, *(const float4*)(W1 + (size_t)(sp * 64 + r) * 4096 + col));
    *(float4*)(pcm1 + sp * 4096 + col) = m;
  } else if (bx < 128) {               // W2 [4096,1024]
    const int sp = bx - 64;
    const int col = tid * 4;
    float4 m = {0.f, 0.f, 0.f, 0.f};
#pragma unroll 8
    for (int r = 0; r < 64; ++r)
      m = max4(m, *(const float4*)(W2 + (size_t)(sp * 64 + r) * 1024 + col));
    *(float4*)(pcm2 + sp * 1024 + col) = m;
  } else {                             // masked absmax of x -> per-block partial
    __shared__ float red[4];
    const int b = bx - 128;            // 1024 blocks
    float lmax = 0.f;
    for (int c = b * 256 + tid; c < 1048576; c += 262144) {
      size_t idx = (size_t)c * 8;
      float mk = fabsf(mask[idx >> 10]);
      float4 m4 = {0.f, 0.f, 0.f, 0.f};
      m4 = max4(m4, *(const float4*)(x + idx));
      m4 = max4(m4, *(const float4*)(x + idx + 4));
      lmax = fmaxf(lmax, fmaxf(fmaxf(m4.x, m4.y), fmaxf(m4.z, m4.w)) * mk);
    }
    for (int s = 32; s; s >>= 1) lmax = fmaxf(lmax, __shfl_down(lmax, s));
    if ((tid & 63) == 0) red[tid >> 6] = lmax;
    __syncthreads();
    if (tid == 0)
      pmaxX[b] = fmaxf(fmaxf(red[0], red[1]), fmaxf(red[2], red[3]));
  }
}

// ===== dispatch 2: quantize x (2048 blk), W1->qW1t (256 blk), W2->qW2t (256 blk) ====
__global__ __launch_bounds__(256) void k_quant(
    const float* __restrict__ x, const float* __restrict__ W1, const float* __restrict__ W2,
    const float* __restrict__ pmaxX, const float* __restrict__ pcm1, const float* __restrict__ pcm2,
    int8_t* __restrict__ qx, int8_t* __restrict__ qw1, int8_t* __restrict__ qw2,
    float* __restrict__ cm1, float* __restrict__ cm2, float* __restrict__ scG) {
  const int bx = blockIdx.x, tid = threadIdx.x;
  if (bx < 2048) {                     // x: reduce pmaxX then quantize 16 f32 -> int8
    __shared__ float red[4];
    float v = fmaxf(fmaxf(pmaxX[tid], pmaxX[tid + 256]),
                    fmaxf(pmaxX[tid + 512], pmaxX[tid + 768]));
    for (int s = 32; s; s >>= 1) v = fmaxf(v, __shfl_down(v, s));
    if ((tid & 63) == 0) red[tid >> 6] = v;
    __syncthreads();
    const float xmax = fmaxf(fmaxf(red[0], red[1]), fmaxf(red[2], red[3]));
    if (bx == 0 && tid == 0) scG[0] = xmax;
    const float s = 127.0f / fmaxf(xmax, EPSQ);
    size_t idx = ((size_t)bx * 256 + tid) * 16;
    union { int8_t p[16]; uint4 v; } u;
#pragma unroll
    for (int i = 0; i < 16; i += 4) {
      float4 f = *(const float4*)(x + idx + i);
      u.p[i] = quant1(f.x, s); u.p[i + 1] = quant1(f.y, s);
      u.p[i + 2] = quant1(f.z, s); u.p[i + 3] = quant1(f.w, s);
    }
    *(uint4*)(qx + idx) = u.v;
  } else if (bx < 2304) {              // W1 [1024,4096] -> qw1t [4096,1024], 4 cols/thr
    int id = (bx - 2048) * 256 + tid;  // 65536 tasks
    int n4 = id & 1023, kc = id >> 10; // col=n4*4, kc in 0..63
    const int col = n4 * 4;
    float4 cm = {0.f, 0.f, 0.f, 0.f};
#pragma unroll
    for (int sp = 0; sp < 16; ++sp) {
      float4 p = *(const float4*)(pcm1 + sp * 4096 + col);
      cm.x = fmaxf(cm.x, p.x); cm.y = fmaxf(cm.y, p.y);
      cm.z = fmaxf(cm.z, p.z); cm.w = fmaxf(cm.w, p.w);
    }
    if (kc == 0) *(float4*)(cm1 + col) = cm;
    const float s0 = 127.0f / fmaxf(cm.x, EPSQ), s1 = 127.0f / fmaxf(cm.y, EPSQ);
    const float s2 = 127.0f / fmaxf(cm.z, EPSQ), s3 = 127.0f / fmaxf(cm.w, EPSQ);
    union { int8_t p[16]; uint4 v; } u0, u1, u2, u3;
#pragma unroll
    for (int j = 0; j < 16; ++j) {
      float4 f = *(const float4*)(W1 + (size_t)(kc * 16 + j) * 4096 + col);
      u0.p[j] = quant1(f.x, s0); u1.p[j] = quant1(f.y, s1);
      u2.p[j] = quant1(f.z, s2); u3.p[j] = quant1(f.w, s3);
    }
    int8_t* base = qw1 + (size_t)col * 1024 + kc * 16;
    *(uint4*)(base) = u0.v;          *(uint4*)(base + 1024) = u1.v;
    *(uint4*)(base + 2048) = u2.v;   *(uint4*)(base + 3072) = u3.v;
  } else {                             // W2 [4096,1024] -> qw2t [1024,4096], 4 cols/thr
    int id = (bx - 2304) * 256 + tid;  // 65536 tasks
    int n4 = id & 255, kc = id >> 8;   // col=n4*4, kc in 0..255
    const int col = n4 * 4;
    float4 cm = {0.f, 0.f, 0.f, 0.f};
#pragma unroll
    for (int sp = 0; sp < 64; ++sp) {
      float4 p = *(const float4*)(pcm2 + sp * 1024 + col);
      cm.x = fmaxf(cm.x, p.x); cm.y = fmaxf(cm.y, p.y);
      cm.z = fmaxf(cm.z, p.z); cm.w = fmaxf(cm.w, p.w);
    }
    if (kc == 0) *(float4*)(cm2 + col) = cm;
    const float s0 = 127.0f / fmaxf(cm.x, EPSQ), s1 = 127.0f / fmaxf(cm.y, EPSQ);
    const float s2 = 127.0f / fmaxf(cm.z, EPSQ), s3 = 127.0f / fmaxf(cm.w, EPSQ);
    union { int8_t p[16]; uint4 v; } u0, u1, u2, u3;
#pragma unroll
    for (int j = 0; j < 16; ++j) {
      float4 f = *(const float4*)(W2 + (size_t)(kc * 16 + j) * 1024 + col);
      u0.p[j] = quant1(f.x, s0); u1.p[j] = quant1(f.y, s1);
      u2.p[j] = quant1(f.z, s2); u3.p[j] = quant1(f.w, s3);
    }
    int8_t* base = qw2 + (size_t)col * 4096 + kc * 16;
    *(uint4*)(base) = u0.v;          *(uint4*)(base + 4096) = u1.v;
    *(uint4*)(base + 8192) = u2.v;   *(uint4*)(base + 12288) = u3.v;
  }
}

// ====== GEMM: A [M,K] x Bt [N,K], 128x128, dbuf BK=64, mfma_i32_32x32x32_i8,
// fragment-order LDS. Grid: x = m-tile (M/128), y = n-tile (N/128).
// LDS tile = 8 fragment blocks of 1KB: block b -> kc=b>>2 (k 32-chunk), t32=b&3
// (m or n 32-row group). Within block: lane l holds row l&31, k=(l>>5)*16..+15.
// MODE 0: h fp16 = relu(deq+bias), per-block masked max -> pmaxH.  MODE 1: f32 out.
template <int MODE>
__global__ __launch_bounds__(256, 4) void gemm_i8(
    const int8_t* __restrict__ A, const int8_t* __restrict__ Bt,
    const float* __restrict__ sxp, const float* __restrict__ cmax,
    const float* __restrict__ bias, const float* __restrict__ mask,
    void* __restrict__ outp, float* __restrict__ pmaxH, int M, int N, int K) {
  __shared__ __align__(16) int8_t lsA[2][8192];
  __shared__ __align__(16) int8_t lsB[2][8192];
  __shared__ float red[4];
  const int tid = threadIdx.x;
  const int wave = tid >> 6, lane = tid & 63;
  const int m0 = blockIdx.x * 128, n0 = blockIdx.y * 128;
  const int wm = (wave & 1) * 64, wn = (wave >> 1) * 64;

  v16i acc[2][2] = {};

  // fragment-order staging: wave stages blocks {wave, wave+4} of A and of B.
  const int frow = lane & 31, fk16 = (lane >> 5) * 16;
  const int bA0 = wave, bA1 = wave + 4;    // kc = b>>2, t32 = b&3
  const int8_t* gA0 = A + (size_t)(m0 + (bA0 & 3) * 32 + frow) * K + (bA0 >> 2) * 32 + fk16;
  const int8_t* gA1 = A + (size_t)(m0 + (bA1 & 3) * 32 + frow) * K + (bA1 >> 2) * 32 + fk16;
  const int8_t* gB0 = Bt + (size_t)(n0 + (bA0 & 3) * 32 + frow) * K + (bA0 >> 2) * 32 + fk16;
  const int8_t* gB1 = Bt + (size_t)(n0 + (bA1 & 3) * 32 + frow) * K + (bA1 >> 2) * 32 + fk16;
  int8_t* dA0 = lsA[0] + bA0 * 1024 + lane * 16;  // [0]/[1] differ by 8192
  int8_t* dA1 = lsA[0] + bA1 * 1024 + lane * 16;
  int8_t* dB0 = lsB[0] + bA0 * 1024 + lane * 16;
  int8_t* dB1 = lsB[0] + bA1 * 1024 + lane * 16;

  const int nsteps = K >> 6;
  async16(gA0, dA0); async16(gA1, dA1);
  async16(gB0, dB0); async16(gB1, dB1);

  const int mI = (wave & 1) * 2;   // A t32 base for this wave
  const int nI = (wave >> 1) * 2;  // B t32 base

  for (int kb = 0; kb < nsteps; ++kb) {
    const int cur = kb & 1;
    const int co = cur * 8192;
    __syncthreads();
    if (kb + 1 < nsteps) {
      const int ko = (kb + 1) << 6;
      const int po = (cur ^ 1) * 8192;
      async16(gA0 + ko, dA0 + po); async16(gA1 + ko, dA1 + po);
      async16(gB0 + ko, dB0 + po); async16(gB1 + ko, dB1 + po);
    }
#pragma unroll
    for (int kc = 0; kc < 2; ++kc) {
      v4i af[2], bf[2];
#pragma unroll
      for (int mt = 0; mt < 2; ++mt)
        af[mt] = *(const v4i*)(lsA[0] + co + (kc * 4 + mI + mt) * 1024 + lane * 16);
#pragma unroll
      for (int nt = 0; nt < 2; ++nt)
        bf[nt] = *(const v4i*)(lsB[0] + co + (kc * 4 + nI + nt) * 1024 + lane * 16);
#pragma unroll
      for (int mt = 0; mt < 2; ++mt)
#pragma unroll
        for (int nt = 0; nt < 2; ++nt)
          acc[mt][nt] = __builtin_amdgcn_mfma_i32_32x32x32_i8(af[mt], bf[nt], acc[mt][nt], 0, 0, 0);
    }
  }

  // epilogue: C/D layout col=lane&31, row=(reg&3)+8*(reg>>2)+4*(lane>>5)
  const float asc = fmaxf(sxp[0], EPSQ) * (1.0f / 127.0f);
  const int cl = lane & 31;
  const int rbase = 4 * (lane >> 5);

  float bsc[2], bv[2];
#pragma unroll
  for (int nt = 0; nt < 2; ++nt) {
    int col = n0 + wn + nt * 32 + cl;
    bsc[nt] = fmaxf(cmax[col], EPSQ) * (1.0f / 127.0f) * asc;
    bv[nt] = bias[col];
  }

  if (MODE == 0) {
    unsigned short* hO = (unsigned short*)outp;
    float lmax = 0.f;
#pragma unroll
    for (int mt = 0; mt < 2; ++mt)
#pragma unroll
      for (int g = 0; g < 4; ++g)
#pragma unroll
        for (int r2 = 0; r2 < 4; ++r2) {
          int row = m0 + wm + mt * 32 + g * 8 + r2 + rbase;
          float mk = fabsf(mask[row]);
          unsigned short* orow = hO + (size_t)row * N + n0 + wn + cl;
#pragma unroll
          for (int nt = 0; nt < 2; ++nt) {
            float v = (float)acc[mt][nt][g * 4 + r2] * bsc[nt] + bv[nt];
            v = fmaxf(v, 0.f);
            orow[nt * 32] = f2h(v);
            lmax = fmaxf(lmax, v * mk);
          }
        }
    for (int s = 32; s; s >>= 1) lmax = fmaxf(lmax, __shfl_down(lmax, s));
    if (lane == 0) red[wave] = lmax;
    __syncthreads();
    if (tid == 0)
      pmaxH[blockIdx.x * gridDim.y + blockIdx.y] =
          fmaxf(fmaxf(red[0], red[1]), fmaxf(red[2], red[3]));
  } else {
    float* oO = (float*)outp;
#pragma unroll
    for (int mt = 0; mt < 2; ++mt)
#pragma unroll
      for (int g = 0; g < 4; ++g)
#pragma unroll
        for (int r2 = 0; r2 < 4; ++r2) {
          int row = m0 + wm + mt * 32 + g * 8 + r2 + rbase;
          float* orow = oO + (size_t)row * N + n0 + wn + cl;
#pragma unroll
          for (int nt = 0; nt < 2; ++nt)
            orow[nt * 32] = (float)acc[mt][nt][g * 4 + r2] * bsc[nt] + bv[nt];
        }
  }
}

// ===== dispatch 4: quantize h (fp16) -> int8; reduce ALL 2048 pmaxH partials =======
__global__ __launch_bounds__(256) void k_quant_h(
    const unsigned short* __restrict__ h, const float* __restrict__ pmaxH,
    float* __restrict__ scG, int8_t* __restrict__ q) {
  __shared__ float red[4];
  const int tid = threadIdx.x;
  float v = 0.f;
#pragma unroll
  for (int j = 0; j < 8; ++j) v = fmaxf(v, pmaxH[tid + 256 * j]);
  for (int s = 32; s; s >>= 1) v = fmaxf(v, __shfl_down(v, s));
  if ((tid & 63) == 0) red[tid >> 6] = v;
  __syncthreads();
  const float hmax = fmaxf(fmaxf(red[0], red[1]), fmaxf(red[2], red[3]));
  if (blockIdx.x == 0 && tid == 0) scG[1] = hmax;
  const float s = 127.0f / fmaxf(hmax, EPSQ);
  size_t idx = ((size_t)blockIdx.x * 256 + tid) * 16;
  union { uint4 v; unsigned short s[8]; } a, b;
  a.v = *(const uint4*)(h + idx);
  b.v = *(const uint4*)(h + idx + 8);
  union { int8_t p[16]; uint4 v; } u;
#pragma unroll
  for (int i = 0; i < 8; ++i) {
    u.p[i] = quant1(h2f(a.s[i]), s);
    u.p[i + 8] = quant1(h2f(b.s[i]), s);
  }
  *(uint4*)(q + idx) = u.v;
}

extern "C" void kernel_launch(void* const* d_in, const int* in_sizes, int n_in,
                              void* d_out, int out_size, void* d_ws, size_t ws_size,
                              hipStream_t stream) {
  const float* x  = (const float*)d_in[0];   // [8192,1024]
  const float* mk = (const float*)d_in[1];   // [8192]
  const float* W1 = (const float*)d_in[2];   // [1024,4096]
  const float* b1 = (const float*)d_in[3];   // [4096]
  const float* W2 = (const float*)d_in[4];   // [4096,1024]
  const float* b2 = (const float*)d_in[5];   // [1024]
  float* out = (float*)d_out;                // [8192,1024]

  float* scG   = (float*)d_ws;               // [8]
  float* pmaxX = scG + 8;                    // [1024]
  float* pmaxH = pmaxX + 1024;               // [2048]
  float* pcm1  = pmaxH + 2048;               // [16*4096]
  float* pcm2  = pcm1 + 65536;               // [64*1024]
  float* cm1   = pcm2 + 65536;               // [4096]
  float* cm2   = cm1 + 4096;                 // [1024]
  int8_t* qx  = (int8_t*)(cm2 + 1024);           // 8 MiB
  int8_t* qw1 = qx  + (size_t)8192 * 1024;       // 4 MiB  [4096][1024]
  int8_t* qw2 = qw1 + (size_t)4096 * 1024;       // 4 MiB  [1024][4096]
  int8_t* qh  = qw2 + (size_t)1024 * 4096;       // 32 MiB
  unsigned short* h = (unsigned short*)(qh + (size_t)8192 * 4096);  // 64 MiB fp16

  k_stats<<<1152, 256, 0, stream>>>(x, mk, W1, W2, pmaxX, pcm1, pcm2);
  k_quant<<<2560, 256, 0, stream>>>(x, W1, W2, pmaxX, pcm1, pcm2,
                                    qx, qw1, qw2, cm1, cm2, scG);
  gemm_i8<0><<<dim3(64, 32), 256, 0, stream>>>(
      qx, qw1, scG, cm1, b1, mk, (void*)h, pmaxH, 8192, 4096, 1024);
  k_quant_h<<<8192, 256, 0, stream>>>(h, pmaxH, scG, qh);
  gemm_i8<1><<<dim3(64, 8), 256, 0, stream>>>(
      qh, qw2, scG + 1, cm2, b2, mk, (void*)out, nullptr, 8192, 1024, 4096);
}

// Round 8
// 250.990 us; speedup vs baseline: 1.1857x; 1.1857x over previous
//
#include <hip/hip_runtime.h>
#include <hip/hip_fp16.h>
#include <stdint.h>

// AQT int8 MLP: M=8192, C=1024, H=4096. All I/O float32.
// Exact path: fake_quant values are q/s (integer q), so xq@wq is exact in int32 MFMA.
// 5 dispatches: stats -> quant(x,W1t,W2t) -> GEMM1(h fp16 + block hmax) -> quant_h -> GEMM2.
//
// All int8 operands live in global memory in MFMA-FRAGMENT ORDER:
//   fragment = 1KB = 32 rows x 32 k; byte lane*16+j <-> (row=lane&31, k=(lane>>5)*16+j)
//   frag index = (rowblk * (K/32) + kblk)
// GEMM staging: one global_load_lds per wave = 1KB fully contiguous burst.
// GEMM: 128x128 block, 2x2 waves, wave-tile 64x64 = 2x2 of mfma_i32_32x32x32_i8,
// BK=64, LDS double-buffer (1 barrier/step). Grid (x=m-tiles, y=n-tiles) for XCD/L2 locality.

#define EPSQ 1e-6f
typedef int v4i __attribute__((ext_vector_type(4)));
typedef int v16i __attribute__((ext_vector_type(16)));

__device__ __forceinline__ int8_t quant1(float x, float s) {
  return (int8_t)(int)fminf(fmaxf(rintf(x * s), -127.f), 127.f);
}
__device__ __forceinline__ void async16(const int8_t* g, int8_t* l) {
  __builtin_amdgcn_global_load_lds(
      (const __attribute__((address_space(1))) void*)g,
      (__attribute__((address_space(3))) void*)l, 16, 0, 0);
}
__device__ __forceinline__ unsigned short f2h(float f) {
  __half h = __float2half(f);
  return *(unsigned short*)&h;
}
__device__ __forceinline__ float h2f(unsigned short u) {
  __half h = *(__half*)&u;
  return __half2float(h);
}
__device__ __forceinline__ float4 max4(float4 m, float4 v) {
  m.x = fmaxf(m.x, fabsf(v.x)); m.y = fmaxf(m.y, fabsf(v.y));
  m.z = fmaxf(m.z, fabsf(v.z)); m.w = fmaxf(m.w, fabsf(v.w));
  return m;
}

// ===== dispatch 1: stats. W1: 16 rowsplits x 4 colgroups; W2: 64 rowsplits;
// x masked absmax: 1024 blk. =====
__global__ __launch_bounds__(256) void k_stats(
    const float* __restrict__ x, const float* __restrict__ mask,
    const float* __restrict__ W1, const float* __restrict__ W2,
    float* __restrict__ pmaxX, float* __restrict__ pcm1, float* __restrict__ pcm2) {
  const int bx = blockIdx.x, tid = threadIdx.x;
  if (bx < 64) {                       // W1 [1024,4096]
    const int sp = bx & 15, cg = bx >> 4;
    const int col = cg * 1024 + tid * 4;
    float4 m = {0.f, 0.f, 0.f, 0.f};
#pragma unroll 8
    for (int r = 0; r < 64; ++r)
      m = max4(m, *(const float4*)(W1 + (size_t)(sp * 64 + r) * 4096 + col));
    *(float4*)(pcm1 + sp * 4096 + col) = m;
  } else if (bx < 128) {               // W2 [4096,1024]
    const int sp = bx - 64;
    const int col = tid * 4;
    float4 m = {0.f, 0.f, 0.f, 0.f};
#pragma unroll 8
    for (int r = 0; r < 64; ++r)
      m = max4(m, *(const float4*)(W2 + (size_t)(sp * 64 + r) * 1024 + col));
    *(float4*)(pcm2 + sp * 1024 + col) = m;
  } else {                             // masked absmax of x -> per-block partial
    __shared__ float red[4];
    const int b = bx - 128;            // 1024 blocks
    float lmax = 0.f;
    for (int c = b * 256 + tid; c < 1048576; c += 262144) {
      size_t idx = (size_t)c * 8;
      float mk = fabsf(mask[idx >> 10]);
      float4 m4 = {0.f, 0.f, 0.f, 0.f};
      m4 = max4(m4, *(const float4*)(x + idx));
      m4 = max4(m4, *(const float4*)(x + idx + 4));
      lmax = fmaxf(lmax, fmaxf(fmaxf(m4.x, m4.y), fmaxf(m4.z, m4.w)) * mk);
    }
    for (int s = 32; s; s >>= 1) lmax = fmaxf(lmax, __shfl_down(lmax, s));
    if ((tid & 63) == 0) red[tid >> 6] = lmax;
    __syncthreads();
    if (tid == 0)
      pmaxX[b] = fmaxf(fmaxf(red[0], red[1]), fmaxf(red[2], red[3]));
  }
}

// ===== dispatch 2: quantize x (2048 blk, frag order), W1->qW1t (256), W2->qW2t (256)
__global__ __launch_bounds__(256) void k_quant(
    const float* __restrict__ x, const float* __restrict__ W1, const float* __restrict__ W2,
    const float* __restrict__ pmaxX, const float* __restrict__ pcm1, const float* __restrict__ pcm2,
    int8_t* __restrict__ qx, int8_t* __restrict__ qw1, int8_t* __restrict__ qw2,
    float* __restrict__ cm1, float* __restrict__ cm2, float* __restrict__ scG) {
  const int bx = blockIdx.x, tid = threadIdx.x;
  if (bx < 2048) {                     // x [8192,1024] -> qx frag order
    __shared__ float red[4];
    float v = fmaxf(fmaxf(pmaxX[tid], pmaxX[tid + 256]),
                    fmaxf(pmaxX[tid + 512], pmaxX[tid + 768]));
    for (int s = 32; s; s >>= 1) v = fmaxf(v, __shfl_down(v, s));
    if ((tid & 63) == 0) red[tid >> 6] = v;
    __syncthreads();
    const float xmax = fmaxf(fmaxf(red[0], red[1]), fmaxf(red[2], red[3]));
    if (bx == 0 && tid == 0) scG[0] = xmax;
    const float s = 127.0f / fmaxf(xmax, EPSQ);
    const int wave = tid >> 6, lane = tid & 63;
    const int f = bx * 4 + wave;                   // frag id; Kf = 1024/32 = 32
    const int r = (f >> 5) * 32 + (lane & 31);
    const int k = (f & 31) * 32 + (lane >> 5) * 16;
    const float4* src = (const float4*)(x + (size_t)r * 1024 + k);
    union { int8_t p[16]; uint4 v; } u;
#pragma unroll
    for (int i = 0; i < 4; ++i) {
      float4 fv = src[i];
      u.p[4 * i] = quant1(fv.x, s);     u.p[4 * i + 1] = quant1(fv.y, s);
      u.p[4 * i + 2] = quant1(fv.z, s); u.p[4 * i + 3] = quant1(fv.w, s);
    }
    *(uint4*)(qx + (size_t)f * 1024 + lane * 16) = u.v;
  } else if (bx < 2304) {              // W1 [1024,4096] -> qw1t frags [4096 n, 1024 k]
    int id = (bx - 2048) * 256 + tid;  // 65536 tasks: 4 cols x 16 k each
    int n4 = id & 1023, kc = id >> 10; // col=n4*4, kc in 0..63 (16-k chunks)
    const int col = n4 * 4;
    float4 cm = {0.f, 0.f, 0.f, 0.f};
#pragma unroll
    for (int sp = 0; sp < 16; ++sp) {
      float4 p = *(const float4*)(pcm1 + sp * 4096 + col);
      cm.x = fmaxf(cm.x, p.x); cm.y = fmaxf(cm.y, p.y);
      cm.z = fmaxf(cm.z, p.z); cm.w = fmaxf(cm.w, p.w);
    }
    if (kc == 0) *(float4*)(cm1 + col) = cm;
    const float s0 = 127.0f / fmaxf(cm.x, EPSQ), s1 = 127.0f / fmaxf(cm.y, EPSQ);
    const float s2 = 127.0f / fmaxf(cm.z, EPSQ), s3 = 127.0f / fmaxf(cm.w, EPSQ);
    union { int8_t p[16]; uint4 v; } u0, u1, u2, u3;
#pragma unroll
    for (int j = 0; j < 16; ++j) {
      float4 f = *(const float4*)(W1 + (size_t)(kc * 16 + j) * 4096 + col);
      u0.p[j] = quant1(f.x, s0); u1.p[j] = quant1(f.y, s1);
      u2.p[j] = quant1(f.z, s2); u3.p[j] = quant1(f.w, s3);
    }
    // frag-order dest: frag=((col>>5)*(1024/32) + (kc>>1)), half=(kc&1)
    int8_t* base = qw1 + ((size_t)(col >> 5) * 32 + (kc >> 1)) * 1024 +
                   (kc & 1) * 512 + (col & 31) * 16;
    *(uint4*)(base) = u0.v;      *(uint4*)(base + 16) = u1.v;
    *(uint4*)(base + 32) = u2.v; *(uint4*)(base + 48) = u3.v;
  } else {                             // W2 [4096,1024] -> qw2t frags [1024 n, 4096 k]
    int id = (bx - 2304) * 256 + tid;  // 65536 tasks
    int n4 = id & 255, kc = id >> 8;   // col=n4*4, kc in 0..255
    const int col = n4 * 4;
    float4 cm = {0.f, 0.f, 0.f, 0.f};
#pragma unroll
    for (int sp = 0; sp < 64; ++sp) {
      float4 p = *(const float4*)(pcm2 + sp * 1024 + col);
      cm.x = fmaxf(cm.x, p.x); cm.y = fmaxf(cm.y, p.y);
      cm.z = fmaxf(cm.z, p.z); cm.w = fmaxf(cm.w, p.w);
    }
    if (kc == 0) *(float4*)(cm2 + col) = cm;
    const float s0 = 127.0f / fmaxf(cm.x, EPSQ), s1 = 127.0f / fmaxf(cm.y, EPSQ);
    const float s2 = 127.0f / fmaxf(cm.z, EPSQ), s3 = 127.0f / fmaxf(cm.w, EPSQ);
    union { int8_t p[16]; uint4 v; } u0, u1, u2, u3;
#pragma unroll
    for (int j = 0; j < 16; ++j) {
      float4 f = *(const float4*)(W2 + (size_t)(kc * 16 + j) * 1024 + col);
      u0.p[j] = quant1(f.x, s0); u1.p[j] = quant1(f.y, s1);
      u2.p[j] = quant1(f.z, s2); u3.p[j] = quant1(f.w, s3);
    }
    int8_t* base = qw2 + ((size_t)(col >> 5) * 128 + (kc >> 1)) * 1024 +
                   (kc & 1) * 512 + (col & 31) * 16;
    *(uint4*)(base) = u0.v;      *(uint4*)(base + 16) = u1.v;
    *(uint4*)(base + 32) = u2.v; *(uint4*)(base + 48) = u3.v;
  }
}

// ====== GEMM: A,Bt in FRAGMENT ORDER ([rowblk][kblk] 1KB frags). 128x128 block,
// dbuf BK=64 (2 k-frags/step), mfma_i32_32x32x32_i8. Staging: 4 waves stage 8 A +
// 8 B frags/step, each as one fully-contiguous 1KB global_load_lds burst.
// Grid: x = m-tile, y = n-tile. MODE 0: h fp16 = relu(deq+bias), masked max ->
// pmaxH. MODE 1: f32 out.
template <int MODE>
__global__ __launch_bounds__(256, 4) void gemm_i8(
    const int8_t* __restrict__ A, const int8_t* __restrict__ Bt,
    const float* __restrict__ sxp, const float* __restrict__ cmax,
    const float* __restrict__ bias, const float* __restrict__ mask,
    void* __restrict__ outp, float* __restrict__ pmaxH, int M, int N, int K) {
  __shared__ __align__(16) int8_t lsA[2][8192];
  __shared__ __align__(16) int8_t lsB[2][8192];
  __shared__ float red[4];
  const int tid = threadIdx.x;
  const int wave = tid >> 6, lane = tid & 63;
  const int m0 = blockIdx.x * 128, n0 = blockIdx.y * 128;
  const int wm = (wave & 1) * 64, wn = (wave >> 1) * 64;
  const int Kf = K >> 5;               // k-frags per 32-row block

  v16i acc[2][2] = {};

  // staging: wave stages LDS blocks b0=wave (kc=0) and b1=wave+4 (kc=1);
  // LDS block b = kc*4 + t32 at offset b*1024. Source frag = (rowblk)*Kf + kc.
  const int b0 = wave, b1 = wave + 4;
  const int8_t* gA0 = A + ((size_t)((m0 >> 5) + (b0 & 3)) * Kf + 0) * 1024 + lane * 16;
  const int8_t* gA1 = A + ((size_t)((m0 >> 5) + (b1 & 3)) * Kf + 1) * 1024 + lane * 16;
  const int8_t* gB0 = Bt + ((size_t)((n0 >> 5) + (b0 & 3)) * Kf + 0) * 1024 + lane * 16;
  const int8_t* gB1 = Bt + ((size_t)((n0 >> 5) + (b1 & 3)) * Kf + 1) * 1024 + lane * 16;
  int8_t* dA0 = lsA[0] + b0 * 1024 + lane * 16;   // buffers differ by +8192
  int8_t* dA1 = lsA[0] + b1 * 1024 + lane * 16;
  int8_t* dB0 = lsB[0] + b0 * 1024 + lane * 16;
  int8_t* dB1 = lsB[0] + b1 * 1024 + lane * 16;

  const int nsteps = K >> 6;           // step = 2 k-frags = 2048B per rowblk
  async16(gA0, dA0); async16(gA1, dA1);
  async16(gB0, dB0); async16(gB1, dB1);

  const int mI = (wave & 1) * 2;   // A t32 base for this wave
  const int nI = (wave >> 1) * 2;  // B t32 base

  for (int kb = 0; kb < nsteps; ++kb) {
    const int cur = kb & 1;
    const int co = cur * 8192;
    __syncthreads();
    if (kb + 1 < nsteps) {
      const size_t ko = (size_t)(kb + 1) * 2048;
      const int po = (cur ^ 1) * 8192;
      async16(gA0 + ko, dA0 + po); async16(gA1 + ko, dA1 + po);
      async16(gB0 + ko, dB0 + po); async16(gB1 + ko, dB1 + po);
    }
#pragma unroll
    for (int kc = 0; kc < 2; ++kc) {
      v4i af[2], bf[2];
#pragma unroll
      for (int mt = 0; mt < 2; ++mt)
        af[mt] = *(const v4i*)(lsA[0] + co + (kc * 4 + mI + mt) * 1024 + lane * 16);
#pragma unroll
      for (int nt = 0; nt < 2; ++nt)
        bf[nt] = *(const v4i*)(lsB[0] + co + (kc * 4 + nI + nt) * 1024 + lane * 16);
#pragma unroll
      for (int mt = 0; mt < 2; ++mt)
#pragma unroll
        for (int nt = 0; nt < 2; ++nt)
          acc[mt][nt] = __builtin_amdgcn_mfma_i32_32x32x32_i8(af[mt], bf[nt], acc[mt][nt], 0, 0, 0);
    }
  }

  // epilogue: C/D layout col=lane&31, row=(reg&3)+8*(reg>>2)+4*(lane>>5)
  const float asc = fmaxf(sxp[0], EPSQ) * (1.0f / 127.0f);
  const int cl = lane & 31;
  const int rbase = 4 * (lane >> 5);

  float bsc[2], bv[2];
#pragma unroll
  for (int nt = 0; nt < 2; ++nt) {
    int col = n0 + wn + nt * 32 + cl;
    bsc[nt] = fmaxf(cmax[col], EPSQ) * (1.0f / 127.0f) * asc;
    bv[nt] = bias[col];
  }

  if (MODE == 0) {
    unsigned short* hO = (unsigned short*)outp;
    float lmax = 0.f;
#pragma unroll
    for (int mt = 0; mt < 2; ++mt)
#pragma unroll
      for (int g = 0; g < 4; ++g)
#pragma unroll
        for (int r2 = 0; r2 < 4; ++r2) {
          int row = m0 + wm + mt * 32 + g * 8 + r2 + rbase;
          float mk = fabsf(mask[row]);
          unsigned short* orow = hO + (size_t)row * N + n0 + wn + cl;
#pragma unroll
          for (int nt = 0; nt < 2; ++nt) {
            float v = (float)acc[mt][nt][g * 4 + r2] * bsc[nt] + bv[nt];
            v = fmaxf(v, 0.f);
            orow[nt * 32] = f2h(v);
            lmax = fmaxf(lmax, v * mk);
          }
        }
    for (int s = 32; s; s >>= 1) lmax = fmaxf(lmax, __shfl_down(lmax, s));
    if (lane == 0) red[wave] = lmax;
    __syncthreads();
    if (tid == 0)
      pmaxH[blockIdx.x * gridDim.y + blockIdx.y] =
          fmaxf(fmaxf(red[0], red[1]), fmaxf(red[2], red[3]));
  } else {
    float* oO = (float*)outp;
#pragma unroll
    for (int mt = 0; mt < 2; ++mt)
#pragma unroll
      for (int g = 0; g < 4; ++g)
#pragma unroll
        for (int r2 = 0; r2 < 4; ++r2) {
          int row = m0 + wm + mt * 32 + g * 8 + r2 + rbase;
          float* orow = oO + (size_t)row * N + n0 + wn + cl;
#pragma unroll
          for (int nt = 0; nt < 2; ++nt)
            orow[nt * 32] = (float)acc[mt][nt][g * 4 + r2] * bsc[nt] + bv[nt];
        }
  }
}

// ===== dispatch 4: h (fp16 [8192,4096]) -> qh frag order; reduce 2048 pmaxH ======
__global__ __launch_bounds__(256) void k_quant_h(
    const unsigned short* __restrict__ h, const float* __restrict__ pmaxH,
    float* __restrict__ scG, int8_t* __restrict__ q) {
  __shared__ float red[4];
  const int tid = threadIdx.x;
  float v = 0.f;
#pragma unroll
  for (int j = 0; j < 8; ++j) v = fmaxf(v, pmaxH[tid + 256 * j]);
  for (int s = 32; s; s >>= 1) v = fmaxf(v, __shfl_down(v, s));
  if ((tid & 63) == 0) red[tid >> 6] = v;
  __syncthreads();
  const float hmax = fmaxf(fmaxf(red[0], red[1]), fmaxf(red[2], red[3]));
  if (blockIdx.x == 0 && tid == 0) scG[1] = hmax;
  const float s = 127.0f / fmaxf(hmax, EPSQ);
  const int wave = tid >> 6, lane = tid & 63;
  const int f = blockIdx.x * 4 + wave;            // frag id; Kf = 4096/32 = 128
  const int r = (f >> 7) * 32 + (lane & 31);
  const int k = (f & 127) * 32 + (lane >> 5) * 16;
  const uint4* hp = (const uint4*)(h + (size_t)r * 4096 + k);
  union { uint4 v; unsigned short s[8]; } a, b;
  a.v = hp[0];
  b.v = hp[1];
  union { int8_t p[16]; uint4 v; } u;
#pragma unroll
  for (int i = 0; i < 8; ++i) {
    u.p[i] = quant1(h2f(a.s[i]), s);
    u.p[i + 8] = quant1(h2f(b.s[i]), s);
  }
  *(uint4*)(q + (size_t)f * 1024 + lane * 16) = u.v;
}

extern "C" void kernel_launch(void* const* d_in, const int* in_sizes, int n_in,
                              void* d_out, int out_size, void* d_ws, size_t ws_size,
                              hipStream_t stream) {
  const float* x  = (const float*)d_in[0];   // [8192,1024]
  const float* mk = (const float*)d_in[1];   // [8192]
  const float* W1 = (const float*)d_in[2];   // [1024,4096]
  const float* b1 = (const float*)d_in[3];   // [4096]
  const float* W2 = (const float*)d_in[4];   // [4096,1024]
  const float* b2 = (const float*)d_in[5];   // [1024]
  float* out = (float*)d_out;                // [8192,1024]

  float* scG   = (float*)d_ws;               // [8]
  float* pmaxX = scG + 8;                    // [1024]
  float* pmaxH = pmaxX + 1024;               // [2048]
  float* pcm1  = pmaxH + 2048;               // [16*4096]
  float* pcm2  = pcm1 + 65536;               // [64*1024]
  float* cm1   = pcm2 + 65536;               // [4096]
  float* cm2   = cm1 + 4096;                 // [1024]
  int8_t* qx  = (int8_t*)(cm2 + 1024);           // 8 MiB  frag order
  int8_t* qw1 = qx  + (size_t)8192 * 1024;       // 4 MiB  frag order [4096 n][1024 k]
  int8_t* qw2 = qw1 + (size_t)4096 * 1024;       // 4 MiB  frag order [1024 n][4096 k]
  int8_t* qh  = qw2 + (size_t)1024 * 4096;       // 32 MiB frag order
  unsigned short* h = (unsigned short*)(qh + (size_t)8192 * 4096);  // 64 MiB fp16

  k_stats<<<1152, 256, 0, stream>>>(x, mk, W1, W2, pmaxX, pcm1, pcm2);
  k_quant<<<2560, 256, 0, stream>>>(x, W1, W2, pmaxX, pcm1, pcm2,
                                    qx, qw1, qw2, cm1, cm2, scG);
  gemm_i8<0><<<dim3(64, 32), 256, 0, stream>>>(
      qx, qw1, scG, cm1, b1, mk, (void*)h, pmaxH, 8192, 4096, 1024);
  k_quant_h<<<8192, 256, 0, stream>>>(h, pmaxH, scG, qh);
  gemm_i8<1><<<dim3(64, 8), 256, 0, stream>>>(
      qh, qw2, scG + 1, cm2, b2, mk, (void*)out, nullptr, 8192, 1024, 4096);
}

// Round 9
// 250.262 us; speedup vs baseline: 1.1891x; 1.0029x over previous
//
#include <hip/hip_runtime.h>
#include <hip/hip_fp16.h>
#include <stdint.h>

// AQT int8 MLP: M=8192, C=1024, H=4096. All I/O float32.
// Exact path: fake_quant values are q/s (integer q), so xq@wq is exact in int32 MFMA.
// 5 dispatches: stats -> quant(x,W1t,W2t) -> GEMM1(h fp16 + block hmax) -> quant_h -> GEMM2.
//
// All int8 operands live in global memory in MFMA-FRAGMENT ORDER:
//   fragment = 1KB = 32 rows x 32 k; byte lane*16+j <-> (row=lane&31, k=(lane>>5)*16+j)
//   frag index = (rowblk * (K/32) + kblk)
// GEMM staging: one global_load_lds per wave-frag = 1KB fully contiguous burst.
// GEMM: 128x128 block, 2x2 waves, wave-tile 64x64 = 2x2 of mfma_i32_32x32x32_i8,
// LDS double-buffer (1 barrier/step). Grid (x=m-tiles, y=n-tiles) for XCD/L2 locality.
// KF = k-frags per step: GEMM1 KF=2 (BK=64, 32KB LDS, 5 blocks/CU),
// GEMM2 KF=4 (BK=128, 64KB LDS — grid-capped at 2 blocks/CU anyway, halves barriers).

#define EPSQ 1e-6f
typedef int v4i __attribute__((ext_vector_type(4)));
typedef int v16i __attribute__((ext_vector_type(16)));

__device__ __forceinline__ int8_t quant1(float x, float s) {
  return (int8_t)(int)fminf(fmaxf(rintf(x * s), -127.f), 127.f);
}
__device__ __forceinline__ void async16(const int8_t* g, int8_t* l) {
  __builtin_amdgcn_global_load_lds(
      (const __attribute__((address_space(1))) void*)g,
      (__attribute__((address_space(3))) void*)l, 16, 0, 0);
}
__device__ __forceinline__ unsigned short f2h(float f) {
  __half h = __float2half(f);
  return *(unsigned short*)&h;
}
__device__ __forceinline__ float h2f(unsigned short u) {
  __half h = *(__half*)&u;
  return __half2float(h);
}
__device__ __forceinline__ float4 max4(float4 m, float4 v) {
  m.x = fmaxf(m.x, fabsf(v.x)); m.y = fmaxf(m.y, fabsf(v.y));
  m.z = fmaxf(m.z, fabsf(v.z)); m.w = fmaxf(m.w, fabsf(v.w));
  return m;
}

// ===== dispatch 1: stats. W1: 16 rowsplits x 4 colgroups; W2: 64 rowsplits;
// x masked absmax: 1024 blk. =====
__global__ __launch_bounds__(256) void k_stats(
    const float* __restrict__ x, const float* __restrict__ mask,
    const float* __restrict__ W1, const float* __restrict__ W2,
    float* __restrict__ pmaxX, float* __restrict__ pcm1, float* __restrict__ pcm2) {
  const int bx = blockIdx.x, tid = threadIdx.x;
  if (bx < 64) {                       // W1 [1024,4096]
    const int sp = bx & 15, cg = bx >> 4;
    const int col = cg * 1024 + tid * 4;
    float4 m = {0.f, 0.f, 0.f, 0.f};
#pragma unroll 8
    for (int r = 0; r < 64; ++r)
      m = max4(m, *(const float4*)(W1 + (size_t)(sp * 64 + r) * 4096 + col));
    *(float4*)(pcm1 + sp * 4096 + col) = m;
  } else if (bx < 128) {               // W2 [4096,1024]
    const int sp = bx - 64;
    const int col = tid * 4;
    float4 m = {0.f, 0.f, 0.f, 0.f};
#pragma unroll 8
    for (int r = 0; r < 64; ++r)
      m = max4(m, *(const float4*)(W2 + (size_t)(sp * 64 + r) * 1024 + col));
    *(float4*)(pcm2 + sp * 1024 + col) = m;
  } else {                             // masked absmax of x -> per-block partial
    __shared__ float red[4];
    const int b = bx - 128;            // 1024 blocks
    float lmax = 0.f;
    for (int c = b * 256 + tid; c < 1048576; c += 262144) {
      size_t idx = (size_t)c * 8;
      float mk = fabsf(mask[idx >> 10]);
      float4 m4 = {0.f, 0.f, 0.f, 0.f};
      m4 = max4(m4, *(const float4*)(x + idx));
      m4 = max4(m4, *(const float4*)(x + idx + 4));
      lmax = fmaxf(lmax, fmaxf(fmaxf(m4.x, m4.y), fmaxf(m4.z, m4.w)) * mk);
    }
    for (int s = 32; s; s >>= 1) lmax = fmaxf(lmax, __shfl_down(lmax, s));
    if ((tid & 63) == 0) red[tid >> 6] = lmax;
    __syncthreads();
    if (tid == 0)
      pmaxX[b] = fmaxf(fmaxf(red[0], red[1]), fmaxf(red[2], red[3]));
  }
}

// ===== dispatch 2: quantize x (2048 blk, frag order), W1->qW1t (256), W2->qW2t (256)
__global__ __launch_bounds__(256) void k_quant(
    const float* __restrict__ x, const float* __restrict__ W1, const float* __restrict__ W2,
    const float* __restrict__ pmaxX, const float* __restrict__ pcm1, const float* __restrict__ pcm2,
    int8_t* __restrict__ qx, int8_t* __restrict__ qw1, int8_t* __restrict__ qw2,
    float* __restrict__ cm1, float* __restrict__ cm2, float* __restrict__ scG) {
  const int bx = blockIdx.x, tid = threadIdx.x;
  if (bx < 2048) {                     // x [8192,1024] -> qx frag order
    __shared__ float red[4];
    float v = fmaxf(fmaxf(pmaxX[tid], pmaxX[tid + 256]),
                    fmaxf(pmaxX[tid + 512], pmaxX[tid + 768]));
    for (int s = 32; s; s >>= 1) v = fmaxf(v, __shfl_down(v, s));
    if ((tid & 63) == 0) red[tid >> 6] = v;
    __syncthreads();
    const float xmax = fmaxf(fmaxf(red[0], red[1]), fmaxf(red[2], red[3]));
    if (bx == 0 && tid == 0) scG[0] = xmax;
    const float s = 127.0f / fmaxf(xmax, EPSQ);
    const int wave = tid >> 6, lane = tid & 63;
    const int f = bx * 4 + wave;                   // frag id; Kf = 1024/32 = 32
    const int r = (f >> 5) * 32 + (lane & 31);
    const int k = (f & 31) * 32 + (lane >> 5) * 16;
    const float4* src = (const float4*)(x + (size_t)r * 1024 + k);
    union { int8_t p[16]; uint4 v; } u;
#pragma unroll
    for (int i = 0; i < 4; ++i) {
      float4 fv = src[i];
      u.p[4 * i] = quant1(fv.x, s);     u.p[4 * i + 1] = quant1(fv.y, s);
      u.p[4 * i + 2] = quant1(fv.z, s); u.p[4 * i + 3] = quant1(fv.w, s);
    }
    *(uint4*)(qx + (size_t)f * 1024 + lane * 16) = u.v;
  } else if (bx < 2304) {              // W1 [1024,4096] -> qw1t frags [4096 n, 1024 k]
    int id = (bx - 2048) * 256 + tid;  // 65536 tasks: 4 cols x 16 k each
    int n4 = id & 1023, kc = id >> 10; // col=n4*4, kc in 0..63 (16-k chunks)
    const int col = n4 * 4;
    float4 cm = {0.f, 0.f, 0.f, 0.f};
#pragma unroll
    for (int sp = 0; sp < 16; ++sp) {
      float4 p = *(const float4*)(pcm1 + sp * 4096 + col);
      cm.x = fmaxf(cm.x, p.x); cm.y = fmaxf(cm.y, p.y);
      cm.z = fmaxf(cm.z, p.z); cm.w = fmaxf(cm.w, p.w);
    }
    if (kc == 0) *(float4*)(cm1 + col) = cm;
    const float s0 = 127.0f / fmaxf(cm.x, EPSQ), s1 = 127.0f / fmaxf(cm.y, EPSQ);
    const float s2 = 127.0f / fmaxf(cm.z, EPSQ), s3 = 127.0f / fmaxf(cm.w, EPSQ);
    union { int8_t p[16]; uint4 v; } u0, u1, u2, u3;
#pragma unroll
    for (int j = 0; j < 16; ++j) {
      float4 f = *(const float4*)(W1 + (size_t)(kc * 16 + j) * 4096 + col);
      u0.p[j] = quant1(f.x, s0); u1.p[j] = quant1(f.y, s1);
      u2.p[j] = quant1(f.z, s2); u3.p[j] = quant1(f.w, s3);
    }
    // frag-order dest: frag=((col>>5)*(1024/32) + (kc>>1)), half=(kc&1)
    int8_t* base = qw1 + ((size_t)(col >> 5) * 32 + (kc >> 1)) * 1024 +
                   (kc & 1) * 512 + (col & 31) * 16;
    *(uint4*)(base) = u0.v;      *(uint4*)(base + 16) = u1.v;
    *(uint4*)(base + 32) = u2.v; *(uint4*)(base + 48) = u3.v;
  } else {                             // W2 [4096,1024] -> qw2t frags [1024 n, 4096 k]
    int id = (bx - 2304) * 256 + tid;  // 65536 tasks
    int n4 = id & 255, kc = id >> 8;   // col=n4*4, kc in 0..255
    const int col = n4 * 4;
    float4 cm = {0.f, 0.f, 0.f, 0.f};
#pragma unroll
    for (int sp = 0; sp < 64; ++sp) {
      float4 p = *(const float4*)(pcm2 + sp * 1024 + col);
      cm.x = fmaxf(cm.x, p.x); cm.y = fmaxf(cm.y, p.y);
      cm.z = fmaxf(cm.z, p.z); cm.w = fmaxf(cm.w, p.w);
    }
    if (kc == 0) *(float4*)(cm2 + col) = cm;
    const float s0 = 127.0f / fmaxf(cm.x, EPSQ), s1 = 127.0f / fmaxf(cm.y, EPSQ);
    const float s2 = 127.0f / fmaxf(cm.z, EPSQ), s3 = 127.0f / fmaxf(cm.w, EPSQ);
    union { int8_t p[16]; uint4 v; } u0, u1, u2, u3;
#pragma unroll
    for (int j = 0; j < 16; ++j) {
      float4 f = *(const float4*)(W2 + (size_t)(kc * 16 + j) * 1024 + col);
      u0.p[j] = quant1(f.x, s0); u1.p[j] = quant1(f.y, s1);
      u2.p[j] = quant1(f.z, s2); u3.p[j] = quant1(f.w, s3);
    }
    int8_t* base = qw2 + ((size_t)(col >> 5) * 128 + (kc >> 1)) * 1024 +
                   (kc & 1) * 512 + (col & 31) * 16;
    *(uint4*)(base) = u0.v;      *(uint4*)(base + 16) = u1.v;
    *(uint4*)(base + 32) = u2.v; *(uint4*)(base + 48) = u3.v;
  }
}

// ====== GEMM: A,Bt in FRAGMENT ORDER ([rowblk][kblk] 1KB frags). 128x128 block,
// dbuf, KF k-frags per step (BK=32*KF), mfma_i32_32x32x32_i8, WPE=min waves/EU.
// Grid: x = m-tile, y = n-tile. MODE 0: h fp16 = relu(deq+bias), masked max ->
// pmaxH. MODE 1: f32 out.
template <int MODE, int KF, int WPE>
__global__ __launch_bounds__(256, WPE) void gemm_i8(
    const int8_t* __restrict__ A, const int8_t* __restrict__ Bt,
    const float* __restrict__ sxp, const float* __restrict__ cmax,
    const float* __restrict__ bias, const float* __restrict__ mask,
    void* __restrict__ outp, float* __restrict__ pmaxH, int M, int N, int K) {
  __shared__ __align__(16) int8_t lsA[2][KF * 4096];
  __shared__ __align__(16) int8_t lsB[2][KF * 4096];
  __shared__ float red[4];
  const int tid = threadIdx.x;
  const int wave = tid >> 6, lane = tid & 63;
  const int m0 = blockIdx.x * 128, n0 = blockIdx.y * 128;
  const int wm = (wave & 1) * 64, wn = (wave >> 1) * 64;
  const int Kf = K >> 5;               // k-frags per 32-row block

  v16i acc[2][2] = {};

  // staging: wave stages LDS blocks {kc*4 + wave} for kc in [0,KF) of A and B.
  // LDS block b = kc*4 + t32 at offset b*1024. Source frag = rowblk*Kf + kc.
  const int8_t* gA[KF]; const int8_t* gB[KF];
  int8_t* dA[KF]; int8_t* dB[KF];
#pragma unroll
  for (int kc = 0; kc < KF; ++kc) {
    gA[kc] = A + ((size_t)((m0 >> 5) + wave) * Kf + kc) * 1024 + lane * 16;
    gB[kc] = Bt + ((size_t)((n0 >> 5) + wave) * Kf + kc) * 1024 + lane * 16;
    dA[kc] = lsA[0] + (kc * 4 + wave) * 1024 + lane * 16;  // buffers differ by KF*4096
    dB[kc] = lsB[0] + (kc * 4 + wave) * 1024 + lane * 16;
  }

  const int nsteps = K / (32 * KF);
#pragma unroll
  for (int kc = 0; kc < KF; ++kc) { async16(gA[kc], dA[kc]); async16(gB[kc], dB[kc]); }

  const int mI = (wave & 1) * 2;   // A t32 base for this wave
  const int nI = (wave >> 1) * 2;  // B t32 base

  for (int kb = 0; kb < nsteps; ++kb) {
    const int cur = kb & 1;
    const int co = cur * (KF * 4096);
    __syncthreads();
    if (kb + 1 < nsteps) {
      const size_t ko = (size_t)(kb + 1) * (KF * 1024);
      const int po = (cur ^ 1) * (KF * 4096);
#pragma unroll
      for (int kc = 0; kc < KF; ++kc) {
        async16(gA[kc] + ko, dA[kc] + po);
        async16(gB[kc] + ko, dB[kc] + po);
      }
    }
#pragma unroll
    for (int kc = 0; kc < KF; ++kc) {
      v4i af[2], bf[2];
#pragma unroll
      for (int mt = 0; mt < 2; ++mt)
        af[mt] = *(const v4i*)(lsA[0] + co + (kc * 4 + mI + mt) * 1024 + lane * 16);
#pragma unroll
      for (int nt = 0; nt < 2; ++nt)
        bf[nt] = *(const v4i*)(lsB[0] + co + (kc * 4 + nI + nt) * 1024 + lane * 16);
#pragma unroll
      for (int mt = 0; mt < 2; ++mt)
#pragma unroll
        for (int nt = 0; nt < 2; ++nt)
          acc[mt][nt] = __builtin_amdgcn_mfma_i32_32x32x32_i8(af[mt], bf[nt], acc[mt][nt], 0, 0, 0);
    }
  }

  // epilogue: C/D layout col=lane&31, row=(reg&3)+8*(reg>>2)+4*(lane>>5)
  const float asc = fmaxf(sxp[0], EPSQ) * (1.0f / 127.0f);
  const int cl = lane & 31;
  const int rbase = 4 * (lane >> 5);

  float bsc[2], bv[2];
#pragma unroll
  for (int nt = 0; nt < 2; ++nt) {
    int col = n0 + wn + nt * 32 + cl;
    bsc[nt] = fmaxf(cmax[col], EPSQ) * (1.0f / 127.0f) * asc;
    bv[nt] = bias[col];
  }

  if (MODE == 0) {
    unsigned short* hO = (unsigned short*)outp;
    float lmax = 0.f;
#pragma unroll
    for (int mt = 0; mt < 2; ++mt)
#pragma unroll
      for (int g = 0; g < 4; ++g)
#pragma unroll
        for (int r2 = 0; r2 < 4; ++r2) {
          int row = m0 + wm + mt * 32 + g * 8 + r2 + rbase;
          float mk = fabsf(mask[row]);
          unsigned short* orow = hO + (size_t)row * N + n0 + wn + cl;
#pragma unroll
          for (int nt = 0; nt < 2; ++nt) {
            float v = (float)acc[mt][nt][g * 4 + r2] * bsc[nt] + bv[nt];
            v = fmaxf(v, 0.f);
            orow[nt * 32] = f2h(v);
            lmax = fmaxf(lmax, v * mk);
          }
        }
    for (int s = 32; s; s >>= 1) lmax = fmaxf(lmax, __shfl_down(lmax, s));
    if (lane == 0) red[wave] = lmax;
    __syncthreads();
    if (tid == 0)
      pmaxH[blockIdx.x * gridDim.y + blockIdx.y] =
          fmaxf(fmaxf(red[0], red[1]), fmaxf(red[2], red[3]));
  } else {
    float* oO = (float*)outp;
#pragma unroll
    for (int mt = 0; mt < 2; ++mt)
#pragma unroll
      for (int g = 0; g < 4; ++g)
#pragma unroll
        for (int r2 = 0; r2 < 4; ++r2) {
          int row = m0 + wm + mt * 32 + g * 8 + r2 + rbase;
          float* orow = oO + (size_t)row * N + n0 + wn + cl;
#pragma unroll
          for (int nt = 0; nt < 2; ++nt)
            orow[nt * 32] = (float)acc[mt][nt][g * 4 + r2] * bsc[nt] + bv[nt];
        }
  }
}

// ===== dispatch 4: h (fp16 [8192,4096]) -> qh frag order; reduce 2048 pmaxH ======
__global__ __launch_bounds__(256) void k_quant_h(
    const unsigned short* __restrict__ h, const float* __restrict__ pmaxH,
    float* __restrict__ scG, int8_t* __restrict__ q) {
  __shared__ float red[4];
  const int tid = threadIdx.x;
  float v = 0.f;
#pragma unroll
  for (int j = 0; j < 8; ++j) v = fmaxf(v, pmaxH[tid + 256 * j]);
  for (int s = 32; s; s >>= 1) v = fmaxf(v, __shfl_down(v, s));
  if ((tid & 63) == 0) red[tid >> 6] = v;
  __syncthreads();
  const float hmax = fmaxf(fmaxf(red[0], red[1]), fmaxf(red[2], red[3]));
  if (blockIdx.x == 0 && tid == 0) scG[1] = hmax;
  const float s = 127.0f / fmaxf(hmax, EPSQ);
  const int wave = tid >> 6, lane = tid & 63;
  const int f = blockIdx.x * 4 + wave;            // frag id; Kf = 4096/32 = 128
  const int r = (f >> 7) * 32 + (lane & 31);
  const int k = (f & 127) * 32 + (lane >> 5) * 16;
  const uint4* hp = (const uint4*)(h + (size_t)r * 4096 + k);
  union { uint4 v; unsigned short s[8]; } a, b;
  a.v = hp[0];
  b.v = hp[1];
  union { int8_t p[16]; uint4 v; } u;
#pragma unroll
  for (int i = 0; i < 8; ++i) {
    u.p[i] = quant1(h2f(a.s[i]), s);
    u.p[i + 8] = quant1(h2f(b.s[i]), s);
  }
  *(uint4*)(q + (size_t)f * 1024 + lane * 16) = u.v;
}

extern "C" void kernel_launch(void* const* d_in, const int* in_sizes, int n_in,
                              void* d_out, int out_size, void* d_ws, size_t ws_size,
                              hipStream_t stream) {
  const float* x  = (const float*)d_in[0];   // [8192,1024]
  const float* mk = (const float*)d_in[1];   // [8192]
  const float* W1 = (const float*)d_in[2];   // [1024,4096]
  const float* b1 = (const float*)d_in[3];   // [4096]
  const float* W2 = (const float*)d_in[4];   // [4096,1024]
  const float* b2 = (const float*)d_in[5];   // [1024]
  float* out = (float*)d_out;                // [8192,1024]

  float* scG   = (float*)d_ws;               // [8]
  float* pmaxX = scG + 8;                    // [1024]
  float* pmaxH = pmaxX + 1024;               // [2048]
  float* pcm1  = pmaxH + 2048;               // [16*4096]
  float* pcm2  = pcm1 + 65536;               // [64*1024]
  float* cm1   = pcm2 + 65536;               // [4096]
  float* cm2   = cm1 + 4096;                 // [1024]
  int8_t* qx  = (int8_t*)(cm2 + 1024);           // 8 MiB  frag order
  int8_t* qw1 = qx  + (size_t)8192 * 1024;       // 4 MiB  frag order [4096 n][1024 k]
  int8_t* qw2 = qw1 + (size_t)4096 * 1024;       // 4 MiB  frag order [1024 n][4096 k]
  int8_t* qh  = qw2 + (size_t)1024 * 4096;       // 32 MiB frag order
  unsigned short* h = (unsigned short*)(qh + (size_t)8192 * 4096);  // 64 MiB fp16

  k_stats<<<1152, 256, 0, stream>>>(x, mk, W1, W2, pmaxX, pcm1, pcm2);
  k_quant<<<2560, 256, 0, stream>>>(x, W1, W2, pmaxX, pcm1, pcm2,
                                    qx, qw1, qw2, cm1, cm2, scG);
  gemm_i8<0, 2, 5><<<dim3(64, 32), 256, 0, stream>>>(
      qx, qw1, scG, cm1, b1, mk, (void*)h, pmaxH, 8192, 4096, 1024);
  k_quant_h<<<8192, 256, 0, stream>>>(h, pmaxH, scG, qh);
  gemm_i8<1, 4, 2><<<dim3(64, 8), 256, 0, stream>>>(
      qh, qw2, scG + 1, cm2, b2, mk, (void*)out, nullptr, 8192, 1024, 4096);
}